// Round 14
// baseline (952.122 us; speedup 1.0000x reference)
//
#include <hip/hip_runtime.h>
#include <hip/hip_cooperative_groups.h>
#include <math.h>

namespace cg = cooperative_groups;

typedef __attribute__((ext_vector_type(8))) short short8;
typedef __attribute__((ext_vector_type(4))) float f32x4;
typedef __attribute__((ext_vector_type(4))) unsigned short u16x4;

#define NBQ 256
#define NBF 5120
#define MROWS 5376
#define E_ 128
#define H_ 256
#define DICTP1 50001
#define GIN_ 808

__device__ __forceinline__ unsigned short f2bf(float x) {
    unsigned int u = __float_as_uint(x);
    u += 0x7fffu + ((u >> 16) & 1u);
    return (unsigned short)(u >> 16);
}
__device__ __forceinline__ float sigmoidf_(float x) { return 1.0f / (1.0f + expf(-x)); }

__device__ __forceinline__ void gload16(const void* g, void* l) {
    __builtin_amdgcn_global_load_lds((const __attribute__((address_space(1))) void*)g,
                                     (__attribute__((address_space(3))) void*)l, 16, 0, 0);
}
// swizzled LDS fragment reads; row stride 128B / 512B; XOR swizzle byte^=(row&7)<<4
__device__ __forceinline__ short8 frag128(const unsigned char* base, int row, int ko) {
    return *reinterpret_cast<const short8*>(base + (row << 7) + ((ko << 1) ^ ((row & 7) << 4)));
}
__device__ __forceinline__ short8 frag512(const unsigned char* base, int row, int ko) {
    return *reinterpret_cast<const short8*>(base + (row << 9) + ((ko << 1) ^ ((row & 7) << 4)));
}

// ============ persistent cooperative LSTM: all 16 steps, c in VGPRs ============
// grid 168 = 21 rowgroups(256 rows) x 8 colgroups(32 hcols x 4 gates = 128 permuted cols)
__global__ __launch_bounds__(512, 1) void lstm_persist(
    const int* __restrict__ qidx, const int* __restrict__ fidx,
    const unsigned short* __restrict__ embb,
    const unsigned short* __restrict__ Wq, const unsigned short* __restrict__ Wf,
    const float* __restrict__ bsq, const float* __restrict__ bsf,
    unsigned short* __restrict__ hb0, unsigned short* __restrict__ hb1)
{
    cg::grid_group gridg = cg::this_grid();
    __shared__ __align__(16) unsigned char Ash[32768];   // [256 rows][64 k] bf16 swizzled
    __shared__ __align__(16) unsigned char Bsh[16384];   // [128 gate-permuted rows][64 k]
    const int tid = threadIdx.x, lane = tid & 63, widx = tid >> 6;   // 8 waves: 4x2
    const int wr = widx >> 1, wc = widx & 1;
    const int rgp = blockIdx.x >> 3, cgp = blockIdx.x & 7;
    const int row0 = rgp << 8;
    const bool isq = (rgp == 0);
    const unsigned short* W = isq ? Wq : Wf;
    const float* bs = isq ? bsq : bsf;
    const int hcol = (cgp << 5) + (wc << 4) + (lane & 15);
    float bsv[4];
    #pragma unroll
    for (int g = 0; g < 4; ++g) bsv[g] = bs[(g << 8) + hcol];
    float creg[16];
    #pragma unroll
    for (int i = 0; i < 16; ++i) creg[i] = 0.f;
    const int sr = lane >> 3, sc = lane & 7;

    const unsigned short* hr = hb0;
    unsigned short* hw = hb1;
    for (int t = 0; t < 16; ++t) {
        f32x4 acc[4][4] = {};
        for (int kc = 0; kc < 6; ++kc) {   // K = 384
            #pragma unroll
            for (int j = 0; j < 4; ++j) {  // A: 32 units of 8 rows, 4 per wave
                const int unit = (widx << 2) + j;
                const int r = (unit << 3) + sr;
                const int ce = (sc ^ (r & 7)) << 3;
                const int n = row0 + r;
                const unsigned short* src;
                if (kc < 2) {
                    const int tok = isq ? qidx[(n << 4) + t] : fidx[((n - NBQ) << 4) + t];
                    src = embb + ((size_t)tok << 7) + (kc << 6) + ce;
                } else {
                    src = hr + ((size_t)n << 8) + ((kc - 2) << 6) + ce;
                }
                gload16(src, Ash + (unit << 10));
            }
            #pragma unroll
            for (int j = 0; j < 2; ++j) {  // W: 16 units, 2 per wave (gate-permuted rows)
                const int unit = (widx << 1) + j;
                const int r = (unit << 3) + sr;
                const int ce = (sc ^ (r & 7)) << 3;
                const int grow = ((r >> 5) << 8) + (cgp << 5) + (((r >> 4) & 1) << 4) + (r & 15);
                gload16(W + (size_t)grow * 384 + (kc << 6) + ce, Bsh + (unit << 10));
            }
            __syncthreads();
            #pragma unroll
            for (int ks = 0; ks < 2; ++ks) {
                const int ko = (ks << 5) + ((lane >> 4) << 3);
                short8 af[4], bfr[4];
                #pragma unroll
                for (int i = 0; i < 4; ++i)
                    af[i] = frag128(Ash, (wr << 6) + (i << 4) + (lane & 15), ko);
                #pragma unroll
                for (int i = 0; i < 4; ++i)
                    bfr[i] = frag128(Bsh, (((i << 1) + wc) << 4) + (lane & 15), ko);
                #pragma unroll
                for (int mi = 0; mi < 4; ++mi)
                    #pragma unroll
                    for (int gi = 0; gi < 4; ++gi)
                        acc[mi][gi] = __builtin_amdgcn_mfma_f32_16x16x32_bf16(af[mi], bfr[gi], acc[mi][gi], 0, 0, 0);
            }
            __syncthreads();
        }
        #pragma unroll
        for (int mi = 0; mi < 4; ++mi) {
            #pragma unroll
            for (int rg4 = 0; rg4 < 4; ++rg4) {
                const int ci = (mi << 2) + rg4;
                const float iv = sigmoidf_(acc[mi][0][rg4] + bsv[0]);
                const float fv = sigmoidf_(acc[mi][1][rg4] + bsv[1]);
                const float gv = tanhf(acc[mi][2][rg4] + bsv[2]);
                const float ov = sigmoidf_(acc[mi][3][rg4] + bsv[3]);
                const float cn = fv * creg[ci] + iv * gv;
                creg[ci] = cn;
                const int m = row0 + (wr << 6) + (mi << 4) + ((lane >> 4) << 2) + rg4;
                hw[((size_t)m << 8) + hcol] = f2bf(ov * tanhf(cn));
            }
        }
        unsigned short* tmp = (unsigned short*)hr; hr = hw; hw = tmp;
        if (t < 15) gridg.sync();
    }
}

// ============ fused g-MLP layers 1-3 + rel0 producer + pair-sum epilogue ============
// (benched r13: 146 us; restructure queued as next delta)
__global__ __launch_bounds__(256) void g123sum(
    const float* __restrict__ UV, const float* __restrict__ Q0,
    const float* __restrict__ sepU, const float* __restrict__ sepV,
    const unsigned short* __restrict__ gw1b, const float* __restrict__ gb1,
    const unsigned short* __restrict__ gw2b, const float* __restrict__ gb2,
    const unsigned short* __restrict__ gw3b, const float* __restrict__ gb3,
    float* __restrict__ rel_sum)
{
    __shared__ __align__(16) unsigned char actA[16384];
    __shared__ __align__(16) unsigned char actB[16384];
    __shared__ __align__(16) unsigned char Wsh[32768];
    const int tid = threadIdx.x, lane = tid & 63, widx = tid >> 6;
    const int grow0 = blockIdx.x << 5;
    {   // rel0 -> actA
        const int r = tid >> 3;
        const int c0 = (tid & 7) << 5;
        const int grow = grow0 + r;
        const int b = grow / 400;
        const int rem = grow - b * 400;
        const int oi = rem % 20, oj = rem / 20;
        const float* up = UV + ((size_t)(b * 20 + oi) << 9);
        const float* vp = UV + ((size_t)(b * 20 + oj) << 9) + 256;
        const float* qp = Q0 + ((size_t)b << 8);
        const float* sup = sepU + (oi << 8);
        const float* svp = sepV + (oj << 8);
        #pragma unroll
        for (int cc = 0; cc < 32; cc += 4) {
            const int c = c0 + cc;
            const float4 u = *(const float4*)(up + c);
            const float4 v = *(const float4*)(vp + c);
            const float4 q = *(const float4*)(qp + c);
            const float4 su = *(const float4*)(sup + c);
            const float4 sv = *(const float4*)(svp + c);
            u16x4 pk;
            pk.x = f2bf(fmaxf(u.x + v.x + q.x + su.x + sv.x, 0.f));
            pk.y = f2bf(fmaxf(u.y + v.y + q.y + su.y + sv.y, 0.f));
            pk.z = f2bf(fmaxf(u.z + v.z + q.z + su.z + sv.z, 0.f));
            pk.w = f2bf(fmaxf(u.w + v.w + q.w + su.w + sv.w, 0.f));
            *(u16x4*)(actA + (r << 9) + (((c << 1) ^ ((r & 7) << 4)))) = pk;
        }
    }
    #pragma unroll 1
    for (int L = 0; L < 3; ++L) {
        const unsigned char* ain = (L & 1) ? actB : actA;
        unsigned char* aout = (L & 1) ? actA : actB;
        const unsigned short* Wp = (L == 0) ? gw1b : (L == 1) ? gw2b : gw3b;
        const float* bl = (L == 0) ? gb1 : (L == 1) ? gb2 : gb3;
        f32x4 acc[2][4] = {};
        for (int kc = 0; kc < 4; ++kc) {
            #pragma unroll
            for (int j = 0; j < 8; ++j) {
                const int unit = (widx << 3) + j;
                const int r = (unit << 3) + (lane >> 3);
                const int ce = ((lane & 7) ^ (r & 7)) << 3;
                gload16(Wp + ((size_t)r << 8) + (kc << 6) + ce, Wsh + (unit << 10));
            }
            __syncthreads();
            #pragma unroll
            for (int ks = 0; ks < 2; ++ks) {
                const int kof = (ks << 5) + ((lane >> 4) << 3);
                const int kcol = (kc << 6) + kof;
                short8 af[2], bfr[4];
                af[0] = frag512(ain, (lane & 15), kcol);
                af[1] = frag512(ain, 16 + (lane & 15), kcol);
                #pragma unroll
                for (int ni = 0; ni < 4; ++ni)
                    bfr[ni] = frag128(Wsh, (widx << 6) + (ni << 4) + (lane & 15), kof);
                #pragma unroll
                for (int mi = 0; mi < 2; ++mi)
                    #pragma unroll
                    for (int ni = 0; ni < 4; ++ni)
                        acc[mi][ni] = __builtin_amdgcn_mfma_f32_16x16x32_bf16(af[mi], bfr[ni], acc[mi][ni], 0, 0, 0);
            }
            __syncthreads();
        }
        float bv[4];
        #pragma unroll
        for (int ni = 0; ni < 4; ++ni) bv[ni] = bl[(widx << 6) + (ni << 4) + (lane & 15)];
        if (L < 2) {
            #pragma unroll
            for (int mi = 0; mi < 2; ++mi)
                #pragma unroll
                for (int ni = 0; ni < 4; ++ni)
                    #pragma unroll
                    for (int rg4 = 0; rg4 < 4; ++rg4) {
                        const float v = fmaxf(acc[mi][ni][rg4] + bv[ni], 0.f);
                        const int row = (mi << 4) + ((lane >> 4) << 2) + rg4;
                        const int col = (widx << 6) + (ni << 4) + (lane & 15);
                        *(unsigned short*)(aout + (row << 9) + (((col << 1) ^ ((row & 7) << 4)))) = f2bf(v);
                    }
        } else {
            const int bstart = grow0 / 400;
            const int rsplit = (bstart + 1) * 400 - grow0;
            const int b1 = (bstart < 255) ? bstart + 1 : 255;
            #pragma unroll
            for (int ni = 0; ni < 4; ++ni) {
                float s0 = 0.f, s1 = 0.f;
                #pragma unroll
                for (int mi = 0; mi < 2; ++mi)
                    #pragma unroll
                    for (int rg4 = 0; rg4 < 4; ++rg4) {
                        const int row = (mi << 4) + ((lane >> 4) << 2) + rg4;
                        const float v = fmaxf(acc[mi][ni][rg4] + bv[ni], 0.f);
                        if (row < rsplit) s0 += v; else s1 += v;
                    }
                s0 += __shfl_xor(s0, 16); s0 += __shfl_xor(s0, 32);
                s1 += __shfl_xor(s1, 16); s1 += __shfl_xor(s1, 32);
                if (lane < 16) {
                    const int col = (widx << 6) + (ni << 4) + lane;
                    atomicAdd(&rel_sum[(bstart << 8) + col], s0);
                    atomicAdd(&rel_sum[(b1 << 8) + col], s1);
                }
            }
        }
    }
}

// ============ bf16 MFMA GEMM (UV / Q0) ============
template <int RELU, int OBF>
__global__ __launch_bounds__(256) void mm_bf16(
    const unsigned short* __restrict__ A, int lda,
    const unsigned short* __restrict__ B, int ldb,
    const float* __restrict__ bias,
    float* __restrict__ Cf, unsigned short* __restrict__ Cb, int ldc, int K)
{
    __shared__ __align__(16) unsigned char Ash[16384];
    __shared__ __align__(16) unsigned char Bsh[16384];
    const int tid = threadIdx.x, lane = tid & 63, widx = tid >> 6;
    const int wr = widx >> 1, wc = widx & 1;
    const int gr = blockIdx.x * 128, gc = blockIdx.y * 128;
    const int rsub = lane >> 3, cgrp = lane & 7;
    f32x4 acc[4][4] = {};
    for (int kt = 0; kt < K; kt += 64) {
        #pragma unroll
        for (int j = 0; j < 4; ++j) {
            const int ch = (widx << 2) + j;
            const int r = (ch << 3) + rsub;
            const int ce = (cgrp ^ (r & 7)) << 3;
            gload16(A + (size_t)(gr + r) * lda + kt + ce, Ash + (ch << 10));
            gload16(B + (size_t)(gc + r) * ldb + kt + ce, Bsh + (ch << 10));
        }
        __syncthreads();
        #pragma unroll
        for (int kk = 0; kk < 64; kk += 32) {
            const int ko = kk + ((lane >> 4) << 3);
            short8 af[4], bfr[4];
            #pragma unroll
            for (int i = 0; i < 4; ++i) {
                af[i]  = frag128(Ash, wr * 64 + i * 16 + (lane & 15), ko);
                bfr[i] = frag128(Bsh, wc * 64 + i * 16 + (lane & 15), ko);
            }
            #pragma unroll
            for (int mi = 0; mi < 4; ++mi)
                #pragma unroll
                for (int ni = 0; ni < 4; ++ni)
                    acc[mi][ni] = __builtin_amdgcn_mfma_f32_16x16x32_bf16(af[mi], bfr[ni], acc[mi][ni], 0, 0, 0);
        }
        __syncthreads();
    }
    const int rq = (lane >> 4) << 2, cl = lane & 15;
    #pragma unroll
    for (int ni = 0; ni < 4; ++ni) {
        const int n = gc + wc * 64 + ni * 16 + cl;
        const float bv = bias ? bias[n] : 0.f;
        #pragma unroll
        for (int mi = 0; mi < 4; ++mi) {
            #pragma unroll
            for (int rg = 0; rg < 4; ++rg) {
                const int m = gr + wr * 64 + mi * 16 + rq + rg;
                float v = acc[mi][ni][rg] + bv;
                if (RELU) v = fmaxf(v, 0.f);
                if (OBF) Cb[(size_t)m * ldc + n] = f2bf(v);
                else     Cf[(size_t)m * ldc + n] = v;
            }
        }
    }
}

// ============ packing / conversion ============
__global__ void cvt_bf16(const float* __restrict__ s, unsigned short* __restrict__ d, int n) {
    for (int i = blockIdx.x * blockDim.x + threadIdx.x; i < n; i += gridDim.x * blockDim.x)
        d[i] = f2bf(s[i]);
}

__global__ void pack_lstm_w(const float* __restrict__ Wih, const float* __restrict__ Whh,
                            const float* __restrict__ bih, const float* __restrict__ bhh,
                            unsigned short* __restrict__ Wc, float* __restrict__ bsum) {
    const int r = blockIdx.x;
    const int cx = threadIdx.x;
    const float v = (cx < E_) ? Wih[r * E_ + cx] : Whh[r * H_ + cx - E_];
    Wc[r * 384 + cx] = f2bf(v);
    if (cx == 0) bsum[r] = bih[r] + bhh[r];
}

__global__ __launch_bounds__(256) void pack_w0(const float* __restrict__ gW0, const float* __restrict__ gb0,
                                               unsigned short* __restrict__ W0ab, unsigned short* __restrict__ W0c,
                                               float* __restrict__ sepU, float* __restrict__ sepV) {
    const int idx = blockIdx.x * 256 + threadIdx.x;
    if (idx < 131072) {
        const int r = idx >> 8, cc = idx & 255;
        const float v = (r < 256) ? gW0[(size_t)r * GIN_ + cc] : gW0[(size_t)(r - 256) * GIN_ + 276 + cc];
        W0ab[idx] = f2bf(v);
    } else if (idx < 196608) {
        const int l = idx - 131072;
        const int r = l >> 8, cc = l & 255;
        W0c[l] = f2bf(gW0[(size_t)r * GIN_ + 552 + cc]);
    } else if (idx < 201728) {
        const int l = idx - 196608;
        const int i = l >> 8, j = l & 255;
        sepU[l] = gW0[(size_t)j * GIN_ + 256 + i] + gb0[j];
    } else {
        const int l = idx - 201728;
        const int i = l >> 8, j = l & 255;
        sepV[l] = gW0[(size_t)j * GIN_ + 532 + i];
    }
}

// ============ fp32 GEMM (f-MLP, small) ============
template <int RELU>
__global__ __launch_bounds__(256) void gemm_nt(
    const float* __restrict__ A, int lda,
    const float* __restrict__ B, int ldb,
    const float* __restrict__ bias,
    float* __restrict__ C, int ldc,
    int M, int N, int K)
{
    __shared__ float As[16][68];
    __shared__ float Bs[16][68];
    const int tid = threadIdx.x;
    const int tx = tid & 15, ty = tid >> 4;
    const int lrow = tid >> 2;
    const int lk = (tid & 3) << 2;
    const int gr = blockIdx.x * 64, gc = blockIdx.y * 64;
    const int ar = gr + lrow;
    const int brr = gc + lrow;
    const float* __restrict__ arow = A + (size_t)ar * lda;
    const float* __restrict__ brow = B + (size_t)brr * ldb;
    const bool aval = ar < M, bval = brr < N;
    float acc[4][4] = {};
    for (int k0 = 0; k0 < K; k0 += 16) {
        float4 a4 = make_float4(0.f, 0.f, 0.f, 0.f), b4 = make_float4(0.f, 0.f, 0.f, 0.f);
        if (aval) a4 = *reinterpret_cast<const float4*>(arow + k0 + lk);
        if (bval) b4 = *reinterpret_cast<const float4*>(brow + k0 + lk);
        As[lk + 0][lrow] = a4.x; As[lk + 1][lrow] = a4.y; As[lk + 2][lrow] = a4.z; As[lk + 3][lrow] = a4.w;
        Bs[lk + 0][lrow] = b4.x; Bs[lk + 1][lrow] = b4.y; Bs[lk + 2][lrow] = b4.z; Bs[lk + 3][lrow] = b4.w;
        __syncthreads();
        #pragma unroll
        for (int kk = 0; kk < 16; ++kk) {
            float a0 = As[kk][ty * 4 + 0], a1 = As[kk][ty * 4 + 1], a2 = As[kk][ty * 4 + 2], a3 = As[kk][ty * 4 + 3];
            float b0 = Bs[kk][tx * 4 + 0], b1 = Bs[kk][tx * 4 + 1], b2 = Bs[kk][tx * 4 + 2], b3 = Bs[kk][tx * 4 + 3];
            acc[0][0] += a0 * b0; acc[0][1] += a0 * b1; acc[0][2] += a0 * b2; acc[0][3] += a0 * b3;
            acc[1][0] += a1 * b0; acc[1][1] += a1 * b1; acc[1][2] += a1 * b2; acc[1][3] += a1 * b3;
            acc[2][0] += a2 * b0; acc[2][1] += a2 * b1; acc[2][2] += a2 * b2; acc[2][3] += a2 * b3;
            acc[3][0] += a3 * b0; acc[3][1] += a3 * b1; acc[3][2] += a3 * b2; acc[3][3] += a3 * b3;
        }
        __syncthreads();
    }
    #pragma unroll
    for (int i = 0; i < 4; ++i)
        #pragma unroll
        for (int jj = 0; jj < 4; ++jj) {
            const int r = gr + ty * 4 + i, cc = gc + tx * 4 + jj;
            if (r < M && cc < N) {
                float v = acc[i][jj] + (bias ? bias[cc] : 0.f);
                if (RELU) v = fmaxf(v, 0.f);
                C[(size_t)r * ldc + cc] = v;
            }
        }
}

extern "C" void kernel_launch(void* const* d_in, const int* in_sizes, int n_in,
                              void* d_out, int out_size, void* d_ws, size_t ws_size,
                              hipStream_t stream)
{
    const int* qidx = (const int*)d_in[0];
    const int* fidx = (const int*)d_in[1];
    const float* emb = (const float*)d_in[2];
    const float* Wih_q = (const float*)d_in[3];
    const float* Whh_q = (const float*)d_in[4];
    const float* bih_q = (const float*)d_in[5];
    const float* bhh_q = (const float*)d_in[6];
    const float* Wih_f = (const float*)d_in[7];
    const float* Whh_f = (const float*)d_in[8];
    const float* bih_f = (const float*)d_in[9];
    const float* bhh_f = (const float*)d_in[10];
    const float* gW0 = (const float*)d_in[11];
    const float* gb0 = (const float*)d_in[12];
    const float* gW1 = (const float*)d_in[13];
    const float* gb1 = (const float*)d_in[14];
    const float* gW2 = (const float*)d_in[15];
    const float* gb2 = (const float*)d_in[16];
    const float* gW3 = (const float*)d_in[17];
    const float* gb3 = (const float*)d_in[18];
    const float* fW0 = (const float*)d_in[19];
    const float* fb0 = (const float*)d_in[20];
    const float* fW1 = (const float*)d_in[21];
    const float* fb1 = (const float*)d_in[22];
    const float* fW2 = (const float*)d_in[23];
    const float* fb2 = (const float*)d_in[24];
    float* out = (float*)d_out;

    // ---- workspace layout (~33 MB; c now lives in VGPRs) ----
    char* w = (char*)d_ws;
    unsigned short* hb0 = (unsigned short*)w;  w += (size_t)MROWS * H_ * 2;
    unsigned short* hb1 = (unsigned short*)w;  w += (size_t)MROWS * H_ * 2;
    unsigned short* embb = (unsigned short*)w; w += (size_t)DICTP1 * E_ * 2;
    unsigned short* Wq = (unsigned short*)w;   w += (size_t)1024 * 384 * 2;
    unsigned short* Wf = (unsigned short*)w;   w += (size_t)1024 * 384 * 2;
    float* bsq = (float*)w;                    w += 1024 * 4;
    float* bsf = (float*)w;                    w += 1024 * 4;
    unsigned short* W0ab = (unsigned short*)w; w += (size_t)512 * 256 * 2;
    unsigned short* W0c = (unsigned short*)w;  w += (size_t)256 * 256 * 2;
    unsigned short* gw1b = (unsigned short*)w; w += (size_t)256 * 256 * 2;
    unsigned short* gw2b = (unsigned short*)w; w += (size_t)256 * 256 * 2;
    unsigned short* gw3b = (unsigned short*)w; w += (size_t)256 * 256 * 2;
    float* sepU = (float*)w;                   w += 20 * 256 * 4;
    float* sepV = (float*)w;                   w += 20 * 256 * 4;
    float* UV = (float*)w;                     w += (size_t)NBF * 512 * 4;
    float* Q0 = (float*)w;                     w += (size_t)NBQ * H_ * 4;
    float* rel_sum = (float*)w;                w += (size_t)NBQ * H_ * 4;
    float* fout1 = (float*)w;                  w += (size_t)NBQ * 256 * 4;
    float* fout2 = (float*)w;                  w += (size_t)NBQ * 512 * 4;

    (void)hipMemsetAsync(hb0, 0, (size_t)MROWS * H_ * 2, stream);
    (void)hipMemsetAsync(rel_sum, 0, (size_t)NBQ * H_ * 4, stream);

    // ---- pack/convert ----
    cvt_bf16<<<2048, 256, 0, stream>>>(emb, embb, DICTP1 * E_);
    pack_lstm_w<<<1024, 384, 0, stream>>>(Wih_q, Whh_q, bih_q, bhh_q, Wq, bsq);
    pack_lstm_w<<<1024, 384, 0, stream>>>(Wih_f, Whh_f, bih_f, bhh_f, Wf, bsf);
    pack_w0<<<808, 256, 0, stream>>>(gW0, gb0, W0ab, W0c, sepU, sepV);
    cvt_bf16<<<64, 256, 0, stream>>>(gW1, gw1b, 256 * 256);
    cvt_bf16<<<64, 256, 0, stream>>>(gW2, gw2b, 256 * 256);
    cvt_bf16<<<64, 256, 0, stream>>>(gW3, gw3b, 256 * 256);

    // ---- persistent cooperative LSTM (16 steps, final h lands in hb0) ----
    {
        void* args[] = {(void*)&qidx, (void*)&fidx, (void*)&embb, (void*)&Wq, (void*)&Wf,
                        (void*)&bsq, (void*)&bsf, (void*)&hb0, (void*)&hb1};
        (void)hipLaunchCooperativeKernel((const void*)lstm_persist, dim3(168), dim3(512), args, 0, stream);
    }

    // ---- U|V and Q0 projections ----
    const unsigned short* fh = hb0 + (size_t)NBQ * H_;
    mm_bf16<0, 0><<<dim3(NBF / 128, 4), 256, 0, stream>>>(fh, H_, W0ab, H_, nullptr, UV, nullptr, 512, H_);
    mm_bf16<0, 0><<<dim3(NBQ / 128, 2), 256, 0, stream>>>(hb0, H_, W0c, H_, nullptr, Q0, nullptr, H_, H_);

    // ---- fused rel0 + g1..g3 + pair-sum ----
    g123sum<<<3200, 256, 0, stream>>>(UV, Q0, sepU, sepV, gw1b, gb1, gw2b, gb2, gw3b, gb3, rel_sum);

    // ---- f-MLP: 256 -> 256 -> 512 -> 32 ----
    gemm_nt<1><<<dim3(NBQ / 64, 256 / 64), 256, 0, stream>>>(rel_sum, H_, fW0, H_, fb0, fout1, H_, NBQ, 256, H_);
    gemm_nt<1><<<dim3(NBQ / 64, 512 / 64), 256, 0, stream>>>(fout1, 256, fW1, 256, fb1, fout2, 512, NBQ, 512, 256);
    gemm_nt<1><<<dim3(NBQ / 64, 1), 256, 0, stream>>>(fout2, 512, fW2, 512, fb2, out, 32, NBQ, 32, 512);
}